// Round 1
// baseline (8000.079 us; speedup 1.0000x reference)
//
#include <hip/hip_runtime.h>

typedef _Float16 f16;
typedef _Float16 f16x8 __attribute__((ext_vector_type(8)));
typedef float f32x4 __attribute__((ext_vector_type(4)));

#define BB 64
#define TT 1024
#define TP 1028
#define DD 512

// ---------------- ws layout (bytes, 4KB-aligned pieces) ----------------
static constexpr size_t SZ_XPAD = (size_t)BB * TP * DD * 2;      // 67,371,008
static constexpr size_t OFF_XA  = 0;
static constexpr size_t OFF_XB  = OFF_XA + SZ_XPAD;
static constexpr size_t OFF_KWA = OFF_XB + SZ_XPAD;              // conv weights, B^T-arranged+swizzled
static constexpr size_t SZ_KWA  = (size_t)480 * 16384;           // 3*5*4*8 blocks x 16KB
static constexpr size_t OFF_WKA = OFF_KWA + SZ_KWA;              // lstm input weights arranged
static constexpr size_t SZ_WKA  = (size_t)128 * 16384;           // 16*8 blocks
static constexpr size_t OFF_WRA = OFF_WKA + SZ_WKA;              // recurrent weights, frag-arranged
static constexpr size_t SZ_WRA  = (size_t)524288 * 2;            // 1MB
static constexpr size_t OFF_SCSH= OFF_WRA + SZ_WRA;              // BN scale/shift
static constexpr size_t SZ_SCSH = (size_t)3072 * 4;
static constexpr size_t OFF_PRE = OFF_SCSH + 4096;               // pad to 4KB
static constexpr size_t SZ_PRE  = (size_t)BB * TT * 2048 * 2;    // 268,435,456
static constexpr size_t OFF_HG  = OFF_PRE + SZ_PRE;              // h exchange buffers
static constexpr size_t SZ_HG   = (size_t)16 * 1024 * 4;
static constexpr size_t OFF_FLAG= OFF_HG + SZ_HG;                // 16 flags, 64B apart

// ---------------- helpers ----------------
__device__ __forceinline__ void gld16(const void* g, void* l) {
  __builtin_amdgcn_global_load_lds(
      (const __attribute__((address_space(1))) unsigned*)g,
      (__attribute__((address_space(3))) unsigned*)l, 16, 0, 0);
}

__device__ __forceinline__ float sigm(float x) {
  x = fminf(fmaxf(x, -30.f), 30.f);
  return 1.f / (1.f + __expf(-x));
}
__device__ __forceinline__ float tanh_(float x) {
  x = fminf(fmaxf(x, -15.f), 15.f);
  float e = __expf(2.f * x);
  return (e - 1.f) / (e + 1.f);
}

// ---------------- prep kernels ----------------
__global__ void prep_scale(const float* __restrict__ cb, const float* __restrict__ gm,
                           const float* __restrict__ bt, const float* __restrict__ mn,
                           const float* __restrict__ vr, float* __restrict__ scsh,
                           unsigned* __restrict__ flags) {
  int i = blockIdx.x * 256 + threadIdx.x;
  if (i < 256) flags[i] = 0u;   // re-zero step counters EVERY launch (graph replay safe)
  if (i < 3 * 512) {
    float rs = rsqrtf(vr[i] + 1e-3f);
    float s = gm[i] * rs;
    scsh[i] = s;
    scsh[1536 + i] = (cb[i] - mn[i]) * s + bt[i];
  }
}

// x f32 [B,T,D] -> xpadA f16 [B,TP,D] with zero halos; also zero xpadB halos
__global__ void prep_x(const float* __restrict__ x, f16* __restrict__ xa, f16* __restrict__ xb) {
  size_t idx = (size_t)blockIdx.x * 256 + threadIdx.x;
  int d = (int)(idx & 511);
  int r = (int)(idx >> 9);
  int t2 = r % TP;
  int b = r / TP;
  int t = t2 - 2;
  bool in = (t >= 0 && t < TT);
  f16 v = in ? (f16)x[((size_t)b * TT + t) * DD + d] : (f16)0.f;
  xa[idx] = v;
  if (!in) xb[idx] = (f16)0.f;
}

// conv kernels f32 [3][5][din][dout] -> arranged swizzled f16 blocks
__global__ void prep_convw(const float* __restrict__ ck, f16* __restrict__ kwa) {
  size_t idx = (size_t)blockIdx.x * 256 + threadIdx.x;
  int dout = (int)(idx & 511);
  int din = (int)((idx >> 9) & 511);
  int k5 = (int)((idx >> 18) % 5);
  int l = (int)(idx / ((size_t)5 << 18));
  f16 v = (f16)ck[idx];
  int blk = ((l * 5 + k5) * 4 + (dout >> 7)) * 8 + (din >> 6);
  int n = dout & 127, kk = din & 63;
  size_t dst = (size_t)blk * 8192 + (size_t)n * 64 + (size_t)(((kk >> 3) ^ (n & 7)) * 8) + (kk & 7);
  kwa[dst] = v;
}

// lstm kernels [512,1024] x2 -> arranged f16 blocks, cols: fw 0..1023, bw 1024..2047
__global__ void prep_wk(const float* __restrict__ wf, const float* __restrict__ wb2, f16* __restrict__ wka) {
  size_t idx = (size_t)blockIdx.x * 256 + threadIdx.x;
  int c = (int)(idx & 2047);
  int din = (int)(idx >> 11);
  float s = (c < 1024) ? wf[(size_t)din * 1024 + c] : wb2[(size_t)din * 1024 + (c - 1024)];
  int blk = (c >> 7) * 8 + (din >> 6);
  int n = c & 127, kk = din & 63;
  size_t dst = (size_t)blk * 8192 + (size_t)n * 64 + (size_t)(((kk >> 3) ^ (n & 7)) * 8) + (kk & 7);
  wka[dst] = (f16)s;
}

// recurrent weights [256,1024] x2 -> per-wave B-fragment layout
__global__ void prep_wr(const float* __restrict__ wf, const float* __restrict__ wb2, f16* __restrict__ wra) {
  size_t idx = (size_t)blockIdx.x * 256 + threadIdx.x;   // 2*256*1024
  int c = (int)(idx & 1023);
  int k = (int)((idx >> 10) & 255);
  int dir = (int)(idx >> 18);
  float s = dir ? wb2[(size_t)k * 1024 + c] : wf[(size_t)k * 1024 + c];
  int gate = c >> 8;
  int u = c & 255;
  int ssub = u >> 4;
  int hf = ssub >> 3, w = ssub & 7;
  int l15 = u & 15;
  int ks = k >> 5, lhi = (k >> 3) & 3, j = k & 7;
  int lane = lhi * 16 + l15;
  size_t dst = ((((size_t)(dir * 2 + hf) * 8 + w) * 4 + gate) * 8 + ks) * 512 + (size_t)lane * 8 + j;
  wra[dst] = (f16)s;
}

// ---------------- conv layer: y = relu(scale*(conv(x)+bias-mean...)+...) ----------------
__global__ __launch_bounds__(256, 3) void conv_gemm(
    const f16* __restrict__ xin, f16* __restrict__ xout,
    const f16* __restrict__ kwb, const float* __restrict__ scl, const float* __restrict__ shl) {
  __shared__ f16 Al[8192];
  __shared__ f16 Bl[8192];
  const int tid = threadIdx.x;
  const int lane = tid & 63;
  const int w = tid >> 6, wm = w >> 1, wn = w & 1;
  const int r15 = lane & 15, lhi = lane >> 4;
  const int wg = blockIdx.x;
  const int tm = wg >> 2, nb = wg & 3;
  const int b = tm >> 3, tblk = tm & 7;
  const size_t abase = (size_t)b * TP + (size_t)tblk * 128;

  int srow[4], asoff[4];
#pragma unroll
  for (int p = 0; p < 4; ++p) {
    int L = tid * 16 + p * 4096;
    int row = L >> 7, ch = (L >> 4) & 7;
    srow[p] = row;
    asoff[p] = (ch ^ (row & 7)) * 8;
  }

  f32x4 acc[4][4] = {};

  for (int k5 = 0; k5 < 5; ++k5) {
    for (int kb = 0; kb < 8; ++kb) {
#pragma unroll
      for (int p = 0; p < 4; ++p) {
        const f16* asrc = xin + (abase + (size_t)(k5 + srow[p])) * DD + kb * 64 + asoff[p];
        gld16(asrc, (char*)Al + tid * 16 + p * 4096);
      }
      const char* bbase = (const char*)kwb + (size_t)((k5 * 4 + nb) * 8 + kb) * 16384;
#pragma unroll
      for (int p = 0; p < 4; ++p)
        gld16(bbase + tid * 16 + p * 4096, (char*)Bl + tid * 16 + p * 4096);
      __syncthreads();
#pragma unroll
      for (int ks = 0; ks < 2; ++ks) {
        f16x8 af[4], bf[4];
#pragma unroll
        for (int m = 0; m < 4; ++m) {
          int row = wm * 64 + m * 16 + r15;
          int rc = (ks * 4 + lhi) ^ (row & 7);
          af[m] = *(const f16x8*)((const char*)Al + row * 128 + rc * 16);
        }
#pragma unroll
        for (int n = 0; n < 4; ++n) {
          int row = wn * 64 + n * 16 + r15;
          int rc = (ks * 4 + lhi) ^ (row & 7);
          bf[n] = *(const f16x8*)((const char*)Bl + row * 128 + rc * 16);
        }
#pragma unroll
        for (int m = 0; m < 4; ++m)
#pragma unroll
          for (int n = 0; n < 4; ++n)
            acc[m][n] = __builtin_amdgcn_mfma_f32_16x16x32_f16(af[m], bf[n], acc[m][n], 0, 0, 0);
      }
      __syncthreads();
    }
  }
#pragma unroll
  for (int n = 0; n < 4; ++n) {
    int c = nb * 128 + wn * 64 + n * 16 + r15;
    float s_ = scl[c], h_ = shl[c];
#pragma unroll
    for (int m = 0; m < 4; ++m) {
      int rl = wm * 64 + m * 16 + lhi * 4;
#pragma unroll
      for (int j = 0; j < 4; ++j) {
        float v = fmaxf(acc[m][n][j] * s_ + h_, 0.f);
        unsigned short us = __builtin_bit_cast(unsigned short, (f16)v);
        unsigned ot = (unsigned)__shfl_xor((int)us, 1, 64);
        if (!(lane & 1)) {
          unsigned pk = (unsigned)us | (ot << 16);
          *(unsigned*)((char*)xout + ((abase + 2 + rl + j) * DD + c) * 2) = pk;
        }
      }
    }
  }
}

// ---------------- LSTM input GEMM: pre[bt][2048] = x @ [Wk_fw|Wk_bw] + bias ----------------
__global__ __launch_bounds__(256, 3) void in_gemm(
    const f16* __restrict__ xin, f16* __restrict__ pre, const f16* __restrict__ wkb,
    const float* __restrict__ bfw, const float* __restrict__ bbw) {
  __shared__ f16 Al[8192];
  __shared__ f16 Bl[8192];
  const int tid = threadIdx.x;
  const int lane = tid & 63;
  const int w = tid >> 6, wm = w >> 1, wn = w & 1;
  const int r15 = lane & 15, lhi = lane >> 4;
  const int wg = blockIdx.x;
  const int tm = wg >> 4, nb = wg & 15;
  const int b = tm >> 3, tblk = tm & 7;
  const size_t abase = (size_t)b * TP + (size_t)tblk * 128 + 2;

  int srow[4], asoff[4];
#pragma unroll
  for (int p = 0; p < 4; ++p) {
    int L = tid * 16 + p * 4096;
    int row = L >> 7, ch = (L >> 4) & 7;
    srow[p] = row;
    asoff[p] = (ch ^ (row & 7)) * 8;
  }

  f32x4 acc[4][4] = {};

  for (int kb = 0; kb < 8; ++kb) {
#pragma unroll
    for (int p = 0; p < 4; ++p) {
      const f16* asrc = xin + (abase + (size_t)srow[p]) * DD + kb * 64 + asoff[p];
      gld16(asrc, (char*)Al + tid * 16 + p * 4096);
    }
    const char* bbase = (const char*)wkb + (size_t)(nb * 8 + kb) * 16384;
#pragma unroll
    for (int p = 0; p < 4; ++p)
      gld16(bbase + tid * 16 + p * 4096, (char*)Bl + tid * 16 + p * 4096);
    __syncthreads();
#pragma unroll
    for (int ks = 0; ks < 2; ++ks) {
      f16x8 af[4], bf[4];
#pragma unroll
      for (int m = 0; m < 4; ++m) {
        int row = wm * 64 + m * 16 + r15;
        int rc = (ks * 4 + lhi) ^ (row & 7);
        af[m] = *(const f16x8*)((const char*)Al + row * 128 + rc * 16);
      }
#pragma unroll
      for (int n = 0; n < 4; ++n) {
        int row = wn * 64 + n * 16 + r15;
        int rc = (ks * 4 + lhi) ^ (row & 7);
        bf[n] = *(const f16x8*)((const char*)Bl + row * 128 + rc * 16);
      }
#pragma unroll
      for (int m = 0; m < 4; ++m)
#pragma unroll
        for (int n = 0; n < 4; ++n)
          acc[m][n] = __builtin_amdgcn_mfma_f32_16x16x32_f16(af[m], bf[n], acc[m][n], 0, 0, 0);
    }
    __syncthreads();
  }
#pragma unroll
  for (int n = 0; n < 4; ++n) {
    int c = nb * 128 + wn * 64 + n * 16 + r15;
    float bias = (c < 1024) ? bfw[c] : bbw[c - 1024];
#pragma unroll
    for (int m = 0; m < 4; ++m) {
      int rl = wm * 64 + m * 16 + lhi * 4;
#pragma unroll
      for (int j = 0; j < 4; ++j) {
        float v = acc[m][n][j] + bias;
        unsigned short us = __builtin_bit_cast(unsigned short, (f16)v);
        unsigned ot = (unsigned)__shfl_xor((int)us, 1, 64);
        if (!(lane & 1)) {
          unsigned pk = (unsigned)us | (ot << 16);
          size_t prow = (size_t)b * TT + tblk * 128 + rl + j;
          *(unsigned*)((char*)pre + (prow * 2048 + c) * 2) = pk;
        }
      }
    }
  }
}

// ---------------- recurrence: 16 wgs (dir x bblk x col-half), pair-sync per step ----------------
__global__ __launch_bounds__(512, 2) void lstm_rec(
    const f16* __restrict__ wra, const f16* __restrict__ pre, float* __restrict__ out,
    unsigned* __restrict__ hg, unsigned* __restrict__ flags) {
  __shared__ f16 hl[16 * 264];   // [16 b][264 u] f16, 16B row-pad -> conflict-free b128 A reads
  const int wg = blockIdx.x;
  const int dir = wg >> 3, bblk = (wg >> 1) & 3, half = wg & 1;
  const int tid = threadIdx.x;
  const int lane = tid & 63, w = tid >> 6;
  const int r15 = lane & 15, lhi = lane >> 4;
  const int ssub = half * 8 + w;
  const int u = ssub * 16 + r15;          // global u of this lane's column
  const int b0 = bblk * 16 + lhi * 4;     // global batch base of this lane's 4 rows
  const int pwg = wg ^ 1;

  // B fragments: 4 gates x 8 ksteps, fully register-resident (128 VGPRs)
  f16x8 bfr[4][8];
  {
    const f16* wb0 = wra + (((size_t)(dir * 2 + half) * 8 + w) * 4) * 8 * 512;
#pragma unroll
    for (int g = 0; g < 4; ++g)
#pragma unroll
      for (int ks = 0; ks < 8; ++ks)
        bfr[g][ks] = *(const f16x8*)(wb0 + ((size_t)g * 8 + ks) * 512 + (size_t)lane * 8);
  }

  for (int i = tid; i < 16 * 264; i += 512) hl[i] = (f16)0.f;
  float cst[4] = {0.f, 0.f, 0.f, 0.f};
  const unsigned short* pr = (const unsigned short*)pre;
  __syncthreads();

  for (int s = 0; s < TT; ++s) {
    const int t = dir ? (TT - 1 - s) : s;
    if (s > 0) {
      if (tid == 0) {
        while (__hip_atomic_load(flags + pwg * 16, __ATOMIC_ACQUIRE, __HIP_MEMORY_SCOPE_AGENT) < (unsigned)s)
          __builtin_amdgcn_s_sleep(2);
      }
      __syncthreads();
      // copy partner h-half (4KB) global -> LDS
#pragma unroll
      for (int q = 0; q < 2; ++q) {
        int idx = tid + q * 512;
        unsigned v = __hip_atomic_load(hg + (size_t)pwg * 1024 + idx, __ATOMIC_RELAXED, __HIP_MEMORY_SCOPE_AGENT);
        int bb = idx >> 6, uu = (idx & 63) * 2;
        *(unsigned*)((char*)hl + bb * 528 + ((half ^ 1) * 128 + uu) * 2) = v;
      }
    }
    __syncthreads();   // h(t-1) fully in hl

    // issue pre loads early (hidden under MFMA)
    unsigned short pv[4][4];
#pragma unroll
    for (int g = 0; g < 4; ++g)
#pragma unroll
      for (int j = 0; j < 4; ++j)
        pv[g][j] = pr[((size_t)(b0 + j) * TT + t) * 2048 + dir * 1024 + g * 256 + u];

    f32x4 accv[4] = {};
#pragma unroll
    for (int ks = 0; ks < 8; ++ks) {
      f16x8 af = *(const f16x8*)((const char*)hl + r15 * 528 + ks * 64 + lhi * 16);
#pragma unroll
      for (int g = 0; g < 4; ++g)
        accv[g] = __builtin_amdgcn_mfma_f32_16x16x32_f16(af, bfr[g][ks], accv[g], 0, 0, 0);
    }

    float hv[4];
#pragma unroll
    for (int j = 0; j < 4; ++j) {
      float zi = accv[0][j] + (float)__builtin_bit_cast(f16, pv[0][j]);
      float zf = accv[1][j] + (float)__builtin_bit_cast(f16, pv[1][j]);
      float zg = accv[2][j] + (float)__builtin_bit_cast(f16, pv[2][j]);
      float zo = accv[3][j] + (float)__builtin_bit_cast(f16, pv[3][j]);
      float ig = sigm(zi), fg = sigm(zf), gg = tanh_(zg), og = sigm(zo);
      float cc = fg * cst[j] + ig * gg;
      cst[j] = cc;
      hv[j] = og * tanh_(cc);
    }

    __syncthreads();   // all A-frag reads done before overwriting hl

    // write own h: LDS + output; publish packed pairs to global exchange buffer
#pragma unroll
    for (int j = 0; j < 4; ++j) {
      int brow = lhi * 4 + j;
      *(f16*)((char*)hl + brow * 528 + u * 2) = (f16)hv[j];
      out[((size_t)(b0 + j) * TT + t) * DD + dir * 256 + u] = hv[j];
      unsigned short us = __builtin_bit_cast(unsigned short, (f16)hv[j]);
      unsigned ot = (unsigned)__shfl_xor((int)us, 1, 64);
      if (!(lane & 1)) {
        unsigned pk = (unsigned)us | (ot << 16);
        int uh = w * 16 + r15;   // local u within half (even)
        __hip_atomic_store(hg + (size_t)wg * 1024 + brow * 64 + (uh >> 1), pk,
                           __ATOMIC_RELAXED, __HIP_MEMORY_SCOPE_AGENT);
      }
    }
    __threadfence();
    __syncthreads();
    if (tid == 0)
      __hip_atomic_store(flags + wg * 16, (unsigned)(s + 1), __ATOMIC_RELEASE, __HIP_MEMORY_SCOPE_AGENT);
  }
}

// ---------------- launch ----------------
extern "C" void kernel_launch(void* const* d_in, const int* in_sizes, int n_in,
                              void* d_out, int out_size, void* d_ws, size_t ws_size,
                              hipStream_t stream) {
  (void)in_sizes; (void)n_in; (void)out_size; (void)ws_size;
  char* ws = (char*)d_ws;
  f16* xa   = (f16*)(ws + OFF_XA);
  f16* xb   = (f16*)(ws + OFF_XB);
  f16* kwa  = (f16*)(ws + OFF_KWA);
  f16* wka  = (f16*)(ws + OFF_WKA);
  f16* wra  = (f16*)(ws + OFF_WRA);
  float* scsh = (float*)(ws + OFF_SCSH);
  f16* pre  = (f16*)(ws + OFF_PRE);
  unsigned* hg    = (unsigned*)(ws + OFF_HG);
  unsigned* flags = (unsigned*)(ws + OFF_FLAG);

  const float* x   = (const float*)d_in[0];
  const float* ck  = (const float*)d_in[1];
  const float* cb  = (const float*)d_in[2];
  const float* gm  = (const float*)d_in[3];
  const float* bt  = (const float*)d_in[4];
  const float* mn  = (const float*)d_in[5];
  const float* vr  = (const float*)d_in[6];
  const float* wkf = (const float*)d_in[7];
  const float* wrf = (const float*)d_in[8];
  const float* bf  = (const float*)d_in[9];
  const float* wkb = (const float*)d_in[10];
  const float* wrb = (const float*)d_in[11];
  const float* bb2 = (const float*)d_in[12];

  prep_scale<<<6, 256, 0, stream>>>(cb, gm, bt, mn, vr, scsh, flags);
  prep_x<<<(BB * TP * DD) / 256, 256, 0, stream>>>(x, xa, xb);
  prep_convw<<<(3 * 5 * 512 * 512) / 256, 256, 0, stream>>>(ck, kwa);
  prep_wk<<<(512 * 2048) / 256, 256, 0, stream>>>(wkf, wkb, wka);
  prep_wr<<<(2 * 256 * 1024) / 256, 256, 0, stream>>>(wrf, wrb, wra);

  conv_gemm<<<2048, 256, 0, stream>>>(xa, xb, kwa,                scsh,          scsh + 1536);
  conv_gemm<<<2048, 256, 0, stream>>>(xb, xa, kwa + 1 * 160 * 8192, scsh + 512,  scsh + 1536 + 512);
  conv_gemm<<<2048, 256, 0, stream>>>(xa, xb, kwa + 2 * 160 * 8192, scsh + 1024, scsh + 1536 + 1024);

  in_gemm<<<8192, 256, 0, stream>>>(xb, pre, wka, bf, bb2);

  lstm_rec<<<16, 512, 0, stream>>>(wra, pre, (float*)d_out, hg, flags);
}

// Round 2
// 4752.018 us; speedup vs baseline: 1.6835x; 1.6835x over previous
//
#include <hip/hip_runtime.h>

typedef _Float16 f16;
typedef _Float16 f16x8 __attribute__((ext_vector_type(8)));
typedef float f32x4 __attribute__((ext_vector_type(4)));

#define BB 64
#define TT 1024
#define TP 1028
#define DD 512

// ---------------- ws layout (bytes, 4KB-aligned pieces) ----------------
static constexpr size_t SZ_XPAD = (size_t)BB * TP * DD * 2;      // 67,371,008
static constexpr size_t OFF_XA  = 0;
static constexpr size_t OFF_XB  = OFF_XA + SZ_XPAD;
static constexpr size_t OFF_KWA = OFF_XB + SZ_XPAD;              // conv weights, B^T-arranged+swizzled
static constexpr size_t SZ_KWA  = (size_t)480 * 16384;           // 3*5*4*8 blocks x 16KB
static constexpr size_t OFF_WKA = OFF_KWA + SZ_KWA;              // lstm input weights arranged
static constexpr size_t SZ_WKA  = (size_t)128 * 16384;           // 16*8 blocks
static constexpr size_t OFF_WRA = OFF_WKA + SZ_WKA;              // recurrent weights, frag-arranged
static constexpr size_t SZ_WRA  = (size_t)524288 * 2;            // 1MB
static constexpr size_t OFF_SCSH= OFF_WRA + SZ_WRA;              // BN scale/shift
static constexpr size_t SZ_SCSH = (size_t)3072 * 4;
static constexpr size_t OFF_PRE = OFF_SCSH + 4096;               // pad to 4KB
static constexpr size_t SZ_PRE  = (size_t)BB * TT * 2048 * 2;    // 268,435,456
static constexpr size_t OFF_HG  = OFF_PRE + SZ_PRE;              // h exchange buffers [wg][2 parity][16b][128uh] f16
static constexpr size_t SZ_HG   = (size_t)16 * 2048 * 4;
static constexpr size_t OFF_FLAG= OFF_HG + SZ_HG;                // 16 flags, 64B apart

// ---------------- helpers ----------------
__device__ __forceinline__ void gld16(const void* g, void* l) {
  __builtin_amdgcn_global_load_lds(
      (const __attribute__((address_space(1))) unsigned*)g,
      (__attribute__((address_space(3))) unsigned*)l, 16, 0, 0);
}

__device__ __forceinline__ float sigm(float x) {
  x = fminf(fmaxf(x, -30.f), 30.f);
  return 1.f / (1.f + __expf(-x));
}
__device__ __forceinline__ float tanh_(float x) {
  x = fminf(fmaxf(x, -15.f), 15.f);
  float e = __expf(2.f * x);
  return (e - 1.f) / (e + 1.f);
}

// ---------------- prep kernels ----------------
__global__ void prep_scale(const float* __restrict__ cb, const float* __restrict__ gm,
                           const float* __restrict__ bt, const float* __restrict__ mn,
                           const float* __restrict__ vr, float* __restrict__ scsh,
                           unsigned* __restrict__ flags) {
  int i = blockIdx.x * 256 + threadIdx.x;
  if (i < 256) flags[i] = 0u;   // re-zero step counters EVERY launch (graph replay safe)
  if (i < 3 * 512) {
    float rs = rsqrtf(vr[i] + 1e-3f);
    float s = gm[i] * rs;
    scsh[i] = s;
    scsh[1536 + i] = (cb[i] - mn[i]) * s + bt[i];
  }
}

// x f32 [B,T,D] -> xpadA f16 [B,TP,D] with zero halos; also zero xpadB halos
__global__ void prep_x(const float* __restrict__ x, f16* __restrict__ xa, f16* __restrict__ xb) {
  size_t idx = (size_t)blockIdx.x * 256 + threadIdx.x;
  int d = (int)(idx & 511);
  int r = (int)(idx >> 9);
  int t2 = r % TP;
  int b = r / TP;
  int t = t2 - 2;
  bool in = (t >= 0 && t < TT);
  f16 v = in ? (f16)x[((size_t)b * TT + t) * DD + d] : (f16)0.f;
  xa[idx] = v;
  if (!in) xb[idx] = (f16)0.f;
}

// conv kernels f32 [3][5][din][dout] -> arranged swizzled f16 blocks
__global__ void prep_convw(const float* __restrict__ ck, f16* __restrict__ kwa) {
  size_t idx = (size_t)blockIdx.x * 256 + threadIdx.x;
  int dout = (int)(idx & 511);
  int din = (int)((idx >> 9) & 511);
  int k5 = (int)((idx >> 18) % 5);
  int l = (int)(idx / ((size_t)5 << 18));
  f16 v = (f16)ck[idx];
  int blk = ((l * 5 + k5) * 4 + (dout >> 7)) * 8 + (din >> 6);
  int n = dout & 127, kk = din & 63;
  size_t dst = (size_t)blk * 8192 + (size_t)n * 64 + (size_t)(((kk >> 3) ^ (n & 7)) * 8) + (kk & 7);
  kwa[dst] = v;
}

// lstm kernels [512,1024] x2 -> arranged f16 blocks, cols: fw 0..1023, bw 1024..2047
__global__ void prep_wk(const float* __restrict__ wf, const float* __restrict__ wb2, f16* __restrict__ wka) {
  size_t idx = (size_t)blockIdx.x * 256 + threadIdx.x;
  int c = (int)(idx & 2047);
  int din = (int)(idx >> 11);
  float s = (c < 1024) ? wf[(size_t)din * 1024 + c] : wb2[(size_t)din * 1024 + (c - 1024)];
  int blk = (c >> 7) * 8 + (din >> 6);
  int n = c & 127, kk = din & 63;
  size_t dst = (size_t)blk * 8192 + (size_t)n * 64 + (size_t)(((kk >> 3) ^ (n & 7)) * 8) + (kk & 7);
  wka[dst] = (f16)s;
}

// recurrent weights [256,1024] x2 -> per-wave B-fragment layout
__global__ void prep_wr(const float* __restrict__ wf, const float* __restrict__ wb2, f16* __restrict__ wra) {
  size_t idx = (size_t)blockIdx.x * 256 + threadIdx.x;   // 2*256*1024
  int c = (int)(idx & 1023);
  int k = (int)((idx >> 10) & 255);
  int dir = (int)(idx >> 18);
  float s = dir ? wb2[(size_t)k * 1024 + c] : wf[(size_t)k * 1024 + c];
  int gate = c >> 8;
  int u = c & 255;
  int ssub = u >> 4;
  int hf = ssub >> 3, w = ssub & 7;
  int l15 = u & 15;
  int ks = k >> 5, lhi = (k >> 3) & 3, j = k & 7;
  int lane = lhi * 16 + l15;
  size_t dst = ((((size_t)(dir * 2 + hf) * 8 + w) * 4 + gate) * 8 + ks) * 512 + (size_t)lane * 8 + j;
  wra[dst] = (f16)s;
}

// ---------------- conv layer: y = relu(scale*conv(x)+shift) ----------------
__global__ __launch_bounds__(256, 3) void conv_gemm(
    const f16* __restrict__ xin, f16* __restrict__ xout,
    const f16* __restrict__ kwb, const float* __restrict__ scl, const float* __restrict__ shl) {
  __shared__ f16 Al[8192];
  __shared__ f16 Bl[8192];
  const int tid = threadIdx.x;
  const int lane = tid & 63;
  const int w = tid >> 6, wm = w >> 1, wn = w & 1;
  const int r15 = lane & 15, lhi = lane >> 4;
  const int wg = blockIdx.x;
  const int tm = wg >> 2, nb = wg & 3;
  const int b = tm >> 3, tblk = tm & 7;
  const size_t abase = (size_t)b * TP + (size_t)tblk * 128;

  int srow[4], asoff[4];
#pragma unroll
  for (int p = 0; p < 4; ++p) {
    int L = tid * 16 + p * 4096;
    int row = L >> 7, ch = (L >> 4) & 7;
    srow[p] = row;
    asoff[p] = (ch ^ (row & 7)) * 8;
  }

  f32x4 acc[4][4] = {};

  for (int k5 = 0; k5 < 5; ++k5) {
    for (int kb = 0; kb < 8; ++kb) {
#pragma unroll
      for (int p = 0; p < 4; ++p) {
        const f16* asrc = xin + (abase + (size_t)(k5 + srow[p])) * DD + kb * 64 + asoff[p];
        gld16(asrc, (char*)Al + tid * 16 + p * 4096);
      }
      const char* bbase = (const char*)kwb + (size_t)((k5 * 4 + nb) * 8 + kb) * 16384;
#pragma unroll
      for (int p = 0; p < 4; ++p)
        gld16(bbase + tid * 16 + p * 4096, (char*)Bl + tid * 16 + p * 4096);
      __syncthreads();
#pragma unroll
      for (int ks = 0; ks < 2; ++ks) {
        f16x8 af[4], bf[4];
#pragma unroll
        for (int m = 0; m < 4; ++m) {
          int row = wm * 64 + m * 16 + r15;
          int rc = (ks * 4 + lhi) ^ (row & 7);
          af[m] = *(const f16x8*)((const char*)Al + row * 128 + rc * 16);
        }
#pragma unroll
        for (int n = 0; n < 4; ++n) {
          int row = wn * 64 + n * 16 + r15;
          int rc = (ks * 4 + lhi) ^ (row & 7);
          bf[n] = *(const f16x8*)((const char*)Bl + row * 128 + rc * 16);
        }
#pragma unroll
        for (int m = 0; m < 4; ++m)
#pragma unroll
          for (int n = 0; n < 4; ++n)
            acc[m][n] = __builtin_amdgcn_mfma_f32_16x16x32_f16(af[m], bf[n], acc[m][n], 0, 0, 0);
      }
      __syncthreads();
    }
  }
#pragma unroll
  for (int n = 0; n < 4; ++n) {
    int c = nb * 128 + wn * 64 + n * 16 + r15;
    float s_ = scl[c], h_ = shl[c];
#pragma unroll
    for (int m = 0; m < 4; ++m) {
      int rl = wm * 64 + m * 16 + lhi * 4;
#pragma unroll
      for (int j = 0; j < 4; ++j) {
        float v = fmaxf(acc[m][n][j] * s_ + h_, 0.f);
        unsigned short us = __builtin_bit_cast(unsigned short, (f16)v);
        unsigned ot = (unsigned)__shfl_xor((int)us, 1, 64);
        if (!(lane & 1)) {
          unsigned pk = (unsigned)us | (ot << 16);
          *(unsigned*)((char*)xout + ((abase + 2 + rl + j) * DD + c) * 2) = pk;
        }
      }
    }
  }
}

// ---------------- LSTM input GEMM: pre[b][t][2048] = x @ [Wk_fw|Wk_bw] + bias ----------------
__global__ __launch_bounds__(256, 3) void in_gemm(
    const f16* __restrict__ xin, f16* __restrict__ pre, const f16* __restrict__ wkb,
    const float* __restrict__ bfw, const float* __restrict__ bbw) {
  __shared__ f16 Al[8192];
  __shared__ f16 Bl[8192];
  const int tid = threadIdx.x;
  const int lane = tid & 63;
  const int w = tid >> 6, wm = w >> 1, wn = w & 1;
  const int r15 = lane & 15, lhi = lane >> 4;
  const int wg = blockIdx.x;
  const int tm = wg >> 4, nb = wg & 15;
  const int b = tm >> 3, tblk = tm & 7;
  const size_t abase = (size_t)b * TP + (size_t)tblk * 128 + 2;

  int srow[4], asoff[4];
#pragma unroll
  for (int p = 0; p < 4; ++p) {
    int L = tid * 16 + p * 4096;
    int row = L >> 7, ch = (L >> 4) & 7;
    srow[p] = row;
    asoff[p] = (ch ^ (row & 7)) * 8;
  }

  f32x4 acc[4][4] = {};

  for (int kb = 0; kb < 8; ++kb) {
#pragma unroll
    for (int p = 0; p < 4; ++p) {
      const f16* asrc = xin + (abase + (size_t)srow[p]) * DD + kb * 64 + asoff[p];
      gld16(asrc, (char*)Al + tid * 16 + p * 4096);
    }
    const char* bbase = (const char*)wkb + (size_t)(nb * 8 + kb) * 16384;
#pragma unroll
    for (int p = 0; p < 4; ++p)
      gld16(bbase + tid * 16 + p * 4096, (char*)Bl + tid * 16 + p * 4096);
    __syncthreads();
#pragma unroll
    for (int ks = 0; ks < 2; ++ks) {
      f16x8 af[4], bf[4];
#pragma unroll
      for (int m = 0; m < 4; ++m) {
        int row = wm * 64 + m * 16 + r15;
        int rc = (ks * 4 + lhi) ^ (row & 7);
        af[m] = *(const f16x8*)((const char*)Al + row * 128 + rc * 16);
      }
#pragma unroll
      for (int n = 0; n < 4; ++n) {
        int row = wn * 64 + n * 16 + r15;
        int rc = (ks * 4 + lhi) ^ (row & 7);
        bf[n] = *(const f16x8*)((const char*)Bl + row * 128 + rc * 16);
      }
#pragma unroll
      for (int m = 0; m < 4; ++m)
#pragma unroll
        for (int n = 0; n < 4; ++n)
          acc[m][n] = __builtin_amdgcn_mfma_f32_16x16x32_f16(af[m], bf[n], acc[m][n], 0, 0, 0);
    }
    __syncthreads();
  }
#pragma unroll
  for (int n = 0; n < 4; ++n) {
    int c = nb * 128 + wn * 64 + n * 16 + r15;
    float bias = (c < 1024) ? bfw[c] : bbw[c - 1024];
#pragma unroll
    for (int m = 0; m < 4; ++m) {
      int rl = wm * 64 + m * 16 + lhi * 4;
#pragma unroll
      for (int j = 0; j < 4; ++j) {
        float v = acc[m][n][j] + bias;
        unsigned short us = __builtin_bit_cast(unsigned short, (f16)v);
        unsigned ot = (unsigned)__shfl_xor((int)us, 1, 64);
        if (!(lane & 1)) {
          unsigned pk = (unsigned)us | (ot << 16);
          size_t prow = (size_t)b * TT + tblk * 128 + rl + j;
          *(unsigned*)((char*)pre + (prow * 2048 + c) * 2) = pk;
        }
      }
    }
  }
}

// ---------------- recurrence: 16 wgs (dir x bblk x col-half) ----------------
// All-relaxed agent-scope protocol; parity double-buffered hg; 2 barriers/step.
__global__ __launch_bounds__(512, 2) void lstm_rec(
    const f16* __restrict__ wra, const f16* __restrict__ pre, float* __restrict__ out,
    unsigned* __restrict__ hg, unsigned* __restrict__ flags) {
  __shared__ f16 hl[16 * 264];   // [16 b][264 u] f16, 16B row-pad
  const int wg = blockIdx.x;
  const int dir = wg >> 3, bblk = (wg >> 1) & 3, half = wg & 1;
  const int tid = threadIdx.x;
  const int lane = tid & 63, w = tid >> 6;
  const int r15 = lane & 15, lhi = lane >> 4;
  const int ssub = half * 8 + w;
  const int u = ssub * 16 + r15;          // global u of this lane's column
  const int uh = w * 16 + r15;            // u local to this wg's half
  const int b0 = bblk * 16 + lhi * 4;     // global batch base of this lane's 4 rows
  const int pwg = wg ^ 1;

  // B fragments: 4 gates x 8 ksteps, register-resident (128 VGPRs)
  f16x8 bfr[4][8];
  {
    const f16* wb0 = wra + (((size_t)(dir * 2 + half) * 8 + w) * 4) * 8 * 512;
#pragma unroll
    for (int g = 0; g < 4; ++g)
#pragma unroll
      for (int ks = 0; ks < 8; ++ks)
        bfr[g][ks] = *(const f16x8*)(wb0 + ((size_t)g * 8 + ks) * 512 + (size_t)lane * 8);
  }

  for (int i = tid; i < 16 * 264; i += 512) hl[i] = (f16)0.f;
  float cst[4] = {0.f, 0.f, 0.f, 0.f};
  const unsigned short* pr = (const unsigned short*)pre;
  // partner-copy destination: [row tid>>5][partner half][(tid&31)*8 bytes]
  char* hl_pdst = (char*)hl + (tid >> 5) * 528 + (half ^ 1) * 256 + (tid & 31) * 8;
  __syncthreads();

  for (int s = 0; s < TT; ++s) {
    const int t = dir ? (TT - 1 - s) : s;

    // pre loads issued before the spin: latency hides under poll/exchange
    unsigned short pv[4][4];
#pragma unroll
    for (int g = 0; g < 4; ++g)
#pragma unroll
      for (int j = 0; j < 4; ++j)
        pv[g][j] = pr[((size_t)(b0 + j) * TT + t) * 2048 + dir * 1024 + g * 256 + u];

    if (s > 0) {
      // all threads poll (relaxed agent: coherent via scope, no invalidate storm)
      while (__hip_atomic_load(flags + pwg * 16, __ATOMIC_RELAXED, __HIP_MEMORY_SCOPE_AGENT) < (unsigned)s) {}
      asm volatile("" ::: "memory");
      // partner h-half: 4KB coalesced 8B loads -> LDS
      unsigned long long v8 = __hip_atomic_load(
          (const unsigned long long*)(hg + (size_t)(pwg * 2 + ((s - 1) & 1)) * 1024) + tid,
          __ATOMIC_RELAXED, __HIP_MEMORY_SCOPE_AGENT);
      *(unsigned long long*)hl_pdst = v8;
    }
    __syncthreads();   // hl fully holds h(t-1) (partner copy + own writes from prev iter)

    f32x4 accv[4] = {};
#pragma unroll
    for (int ks = 0; ks < 8; ++ks) {
      f16x8 af = *(const f16x8*)((const char*)hl + r15 * 528 + ks * 64 + lhi * 16);
#pragma unroll
      for (int g = 0; g < 4; ++g)
        accv[g] = __builtin_amdgcn_mfma_f32_16x16x32_f16(af, bfr[g][ks], accv[g], 0, 0, 0);
    }

    float hv[4];
#pragma unroll
    for (int j = 0; j < 4; ++j) {
      float zi = accv[0][j] + (float)__builtin_bit_cast(f16, pv[0][j]);
      float zf = accv[1][j] + (float)__builtin_bit_cast(f16, pv[1][j]);
      float zg = accv[2][j] + (float)__builtin_bit_cast(f16, pv[2][j]);
      float zo = accv[3][j] + (float)__builtin_bit_cast(f16, pv[3][j]);
      float ig = sigm(zi), fg = sigm(zf), gg = tanh_(zg), og = sigm(zo);
      float cc = fg * cst[j] + ig * gg;
      cst[j] = cc;
      hv[j] = og * tanh_(cc);
    }

    // publish own h-half to hg[parity s&1] (packed pairs, relaxed agent)
    unsigned short us0 = __builtin_bit_cast(unsigned short, (f16)hv[0]);
    unsigned short us1 = __builtin_bit_cast(unsigned short, (f16)hv[1]);
    unsigned short us2 = __builtin_bit_cast(unsigned short, (f16)hv[2]);
    unsigned short us3 = __builtin_bit_cast(unsigned short, (f16)hv[3]);
    {
      unsigned* slot = hg + (size_t)(wg * 2 + (s & 1)) * 1024;
      unsigned o0 = (unsigned)__shfl_xor((int)us0, 1, 64);
      unsigned o1 = (unsigned)__shfl_xor((int)us1, 1, 64);
      unsigned o2 = (unsigned)__shfl_xor((int)us2, 1, 64);
      unsigned o3 = (unsigned)__shfl_xor((int)us3, 1, 64);
      if (!(lane & 1)) {
        int base = (lhi * 4) * 64 + (uh >> 1);
        __hip_atomic_store(slot + base,       (unsigned)us0 | (o0 << 16), __ATOMIC_RELAXED, __HIP_MEMORY_SCOPE_AGENT);
        __hip_atomic_store(slot + base + 64,  (unsigned)us1 | (o1 << 16), __ATOMIC_RELAXED, __HIP_MEMORY_SCOPE_AGENT);
        __hip_atomic_store(slot + base + 128, (unsigned)us2 | (o2 << 16), __ATOMIC_RELAXED, __HIP_MEMORY_SCOPE_AGENT);
        __hip_atomic_store(slot + base + 192, (unsigned)us3 | (o3 << 16), __ATOMIC_RELAXED, __HIP_MEMORY_SCOPE_AGENT);
      }
    }
    asm volatile("s_waitcnt vmcnt(0)" ::: "memory");  // hg stores complete at coherence point
    __syncthreads();   // all waves: hl reads done AND hg stores drained
    if (tid == 0)
      __hip_atomic_store(flags + wg * 16, (unsigned)(s + 1), __ATOMIC_RELAXED, __HIP_MEMORY_SCOPE_AGENT);

    // off critical path: own h into LDS (covered by next step's barrier) + output stores
#pragma unroll
    for (int j = 0; j < 4; ++j) {
      *(f16*)((char*)hl + (lhi * 4 + j) * 528 + u * 2) = (f16)hv[j];
      out[((size_t)(b0 + j) * TT + t) * DD + dir * 256 + u] = hv[j];
    }
  }
}

// ---------------- launch ----------------
extern "C" void kernel_launch(void* const* d_in, const int* in_sizes, int n_in,
                              void* d_out, int out_size, void* d_ws, size_t ws_size,
                              hipStream_t stream) {
  (void)in_sizes; (void)n_in; (void)out_size; (void)ws_size;
  char* ws = (char*)d_ws;
  f16* xa   = (f16*)(ws + OFF_XA);
  f16* xb   = (f16*)(ws + OFF_XB);
  f16* kwa  = (f16*)(ws + OFF_KWA);
  f16* wka  = (f16*)(ws + OFF_WKA);
  f16* wra  = (f16*)(ws + OFF_WRA);
  float* scsh = (float*)(ws + OFF_SCSH);
  f16* pre  = (f16*)(ws + OFF_PRE);
  unsigned* hg    = (unsigned*)(ws + OFF_HG);
  unsigned* flags = (unsigned*)(ws + OFF_FLAG);

  const float* x   = (const float*)d_in[0];
  const float* ck  = (const float*)d_in[1];
  const float* cb  = (const float*)d_in[2];
  const float* gm  = (const float*)d_in[3];
  const float* bt  = (const float*)d_in[4];
  const float* mn  = (const float*)d_in[5];
  const float* vr  = (const float*)d_in[6];
  const float* wkf = (const float*)d_in[7];
  const float* wrf = (const float*)d_in[8];
  const float* bf  = (const float*)d_in[9];
  const float* wkb = (const float*)d_in[10];
  const float* wrb = (const float*)d_in[11];
  const float* bb2 = (const float*)d_in[12];

  prep_scale<<<6, 256, 0, stream>>>(cb, gm, bt, mn, vr, scsh, flags);
  prep_x<<<(BB * TP * DD) / 256, 256, 0, stream>>>(x, xa, xb);
  prep_convw<<<(3 * 5 * 512 * 512) / 256, 256, 0, stream>>>(ck, kwa);
  prep_wk<<<(512 * 2048) / 256, 256, 0, stream>>>(wkf, wkb, wka);
  prep_wr<<<(2 * 256 * 1024) / 256, 256, 0, stream>>>(wrf, wrb, wra);

  conv_gemm<<<2048, 256, 0, stream>>>(xa, xb, kwa,                  scsh,          scsh + 1536);
  conv_gemm<<<2048, 256, 0, stream>>>(xb, xa, kwa + 1 * 160 * 8192, scsh + 512,   scsh + 1536 + 512);
  conv_gemm<<<2048, 256, 0, stream>>>(xa, xb, kwa + 2 * 160 * 8192, scsh + 1024,  scsh + 1536 + 1024);

  in_gemm<<<8192, 256, 0, stream>>>(xb, pre, wka, bf, bb2);

  lstm_rec<<<16, 512, 0, stream>>>(wra, pre, (float*)d_out, hg, flags);
}